// Round 2
// baseline (714.838 us; speedup 1.0000x reference)
//
#include <hip/hip_runtime.h>

#define SSIM_H 512
#define SSIM_W 512
#define SSIM_PLANES 96
#define TILE_H 32
#define TILE_W 64
#define TOTAL_BLOCKS (8 * 16 * 96)
#define N_TOTAL 25165824.0

// 11-tap Gaussian, sigma=1.5, normalized (matches reference _gaussian_window).
__global__ __launch_bounds__(256, 3)
void ssim_l1_kernel(const float* __restrict__ pred,
                    const float* __restrict__ targ,
                    double* __restrict__ accum,
                    float* __restrict__ out) {
  const float w[11] = {
      0.00102838f, 0.00759876f, 0.03600077f, 0.10936069f, 0.21300553f,
      0.26601172f, 0.21300553f, 0.10936069f, 0.03600077f, 0.00759876f,
      0.00102838f};

  // 5 horizontal-conv planes: x, y, x*x, y*y, x*y. 42 halo rows x 64 cols.
  __shared__ __align__(16) float hc[5][TILE_H + 10][TILE_W];
  __shared__ float red[2][4];

  const int tid = (int)threadIdx.x;
  const int bx = (int)blockIdx.x, by = (int)blockIdx.y;
  const int row0 = by * TILE_H;  // first core row of tile
  const int col0 = bx * TILE_W;
  const size_t pbase = (size_t)blockIdx.z * (SSIM_H * SSIM_W);
  const float* __restrict__ xp = pred + pbase;
  const float* __restrict__ yp = targ + pbase;
  const bool xfast = (bx >= 1) && (bx <= 6);  // aligned window fully in-bounds

  float l1 = 0.0f;

  // ---- Phase A: horizontal conv for halo rows -5..36, 4-col chunks ----
  auto processA = [&](int item) {
    const int r = item >> 4;        // 0..41
    const int chunk = item & 15;
    const int irow = row0 - 5 + r;
    const int cb = col0 + (chunk << 2);  // first core col (multiple of 4)

    // A/B hold cols cb-8 .. cb+11 (5 aligned float4). Window = elements 3..16.
    float A[20], B[20];
    if ((unsigned)irow < (unsigned)SSIM_H) {
      const float* __restrict__ xr = xp + (size_t)irow * SSIM_W;
      const float* __restrict__ yr = yp + (size_t)irow * SSIM_W;
      if (xfast) {
        const float4* __restrict__ xa = (const float4*)(xr + (cb - 8));
        const float4* __restrict__ ya = (const float4*)(yr + (cb - 8));
#pragma unroll
        for (int q = 0; q < 5; ++q) {
          const float4 va = xa[q];
          const float4 vb = ya[q];
          A[4 * q + 0] = va.x; A[4 * q + 1] = va.y;
          A[4 * q + 2] = va.z; A[4 * q + 3] = va.w;
          B[4 * q + 0] = vb.x; B[4 * q + 1] = vb.y;
          B[4 * q + 2] = vb.z; B[4 * q + 3] = vb.w;
        }
      } else {
#pragma unroll
        for (int j = 0; j < 20; ++j) {
          const int c = cb - 8 + j;
          const bool ok = (unsigned)c < (unsigned)SSIM_W;
          A[j] = ok ? xr[c] : 0.0f;
          B[j] = ok ? yr[c] : 0.0f;
        }
      }
    } else {
#pragma unroll
      for (int j = 0; j < 20; ++j) { A[j] = 0.0f; B[j] = 0.0f; }
    }

    // L1 term on core rows; core cols are elements 8..11.
    if (r >= 5 && r < 37) {
#pragma unroll
      for (int o = 0; o < 4; ++o) l1 += fabsf(A[8 + o] - B[8 + o]);
    }

    float hx[4] = {0, 0, 0, 0}, hy[4] = {0, 0, 0, 0};
    float hxx[4] = {0, 0, 0, 0}, hyy[4] = {0, 0, 0, 0}, hxy[4] = {0, 0, 0, 0};
#pragma unroll
    for (int j = 0; j < 14; ++j) {  // window element j = col cb-5+j
      const float a = A[3 + j], b = B[3 + j];
      const float aa = a * a, bb = b * b, ab = a * b;
#pragma unroll
      for (int o = 0; o < 4; ++o) {
        const int k = j - o;
        if (k >= 0 && k < 11) {
          hx[o] += w[k] * a;
          hy[o] += w[k] * b;
          hxx[o] += w[k] * aa;
          hyy[o] += w[k] * bb;
          hxy[o] += w[k] * ab;
        }
      }
    }
    const int cc = chunk << 2;
    *(float4*)&hc[0][r][cc] = make_float4(hx[0], hx[1], hx[2], hx[3]);
    *(float4*)&hc[1][r][cc] = make_float4(hy[0], hy[1], hy[2], hy[3]);
    *(float4*)&hc[2][r][cc] = make_float4(hxx[0], hxx[1], hxx[2], hxx[3]);
    *(float4*)&hc[3][r][cc] = make_float4(hyy[0], hyy[1], hyy[2], hyy[3]);
    *(float4*)&hc[4][r][cc] = make_float4(hxy[0], hxy[1], hxy[2], hxy[3]);
  };

#pragma unroll
  for (int rd = 0; rd < 3; ++rd) {
    const int item = tid + rd * 256;
    if (item < 42 * 16) processA(item);
  }

  __syncthreads();

  // ---- Phase B: vertical conv + SSIM. 16 col-groups x 16 2-row bands. ----
  float ssim_sum = 0.0f;
  {
    const int g = tid & 15;   // float4 col group
    const int b = tid >> 4;   // 2-row band
    float acc[5][2][4];
#pragma unroll
    for (int p = 0; p < 5; ++p)
#pragma unroll
      for (int rr = 0; rr < 2; ++rr)
#pragma unroll
        for (int q = 0; q < 4; ++q) acc[p][rr][q] = 0.0f;

#pragma unroll
    for (int j = 0; j < 12; ++j) {
#pragma unroll
      for (int p = 0; p < 5; ++p) {
        const float4 v = *(const float4*)&hc[p][2 * b + j][g * 4];
        const float vv[4] = {v.x, v.y, v.z, v.w};
#pragma unroll
        for (int q = 0; q < 4; ++q) {
          if (j < 11) acc[p][0][q] += w[j] * vv[q];
          if (j >= 1) acc[p][1][q] += w[j - 1] * vv[q];
        }
      }
    }

    const float C1v = 1.0e-4f, C2v = 9.0e-4f;
#pragma unroll
    for (int rr = 0; rr < 2; ++rr) {
#pragma unroll
      for (int q = 0; q < 4; ++q) {
        const float mu1 = acc[0][rr][q], mu2 = acc[1][rr][q];
        const float cxx = acc[2][rr][q], cyy = acc[3][rr][q], cxy = acc[4][rr][q];
        const float m11 = mu1 * mu1, m22 = mu2 * mu2, m12 = mu1 * mu2;
        const float num = (2.0f * m12 + C1v) * (2.0f * (cxy - m12) + C2v);
        const float den = (m11 + m22 + C1v) * ((cxx - m11) + (cyy - m22) + C2v);
        ssim_sum += num / den;
      }
    }
  }

  // ---- Reduction: wave shuffle -> LDS -> block -> global double atomics ----
  float v0 = l1, v1 = ssim_sum;
#pragma unroll
  for (int off = 32; off > 0; off >>= 1) {
    v0 += __shfl_down(v0, off, 64);
    v1 += __shfl_down(v1, off, 64);
  }
  const int lane = tid & 63, wid = tid >> 6;
  if (lane == 0) { red[0][wid] = v0; red[1][wid] = v1; }
  __syncthreads();
  if (tid == 0) {
    const double L = (double)red[0][0] + (double)red[0][1] +
                     (double)red[0][2] + (double)red[0][3];
    const double S = (double)red[1][0] + (double)red[1][1] +
                     (double)red[1][2] + (double)red[1][3];
    atomicAdd(accum + 0, L);
    atomicAdd(accum + 1, S);
    __threadfence();  // make partial sums visible before signaling done
    unsigned prev = atomicAdd((unsigned*)(accum + 2), 1u);
    if (prev == TOTAL_BLOCKS - 1) {
      // Last block: all adds are globally visible (each was fenced before
      // its counter increment). Read via device-scope atomics to bypass L1.
      const double Ls = atomicAdd(accum + 0, 0.0);
      const double Ss = atomicAdd(accum + 1, 0.0);
      const double invN = 1.0 / N_TOTAL;
      out[0] = (float)(0.84 * (Ls * invN) + 0.16 * (1.0 - Ss * invN));
    }
  }
}

extern "C" void kernel_launch(void* const* d_in, const int* in_sizes, int n_in,
                              void* d_out, int out_size, void* d_ws, size_t ws_size,
                              hipStream_t stream) {
  const float* pred = (const float*)d_in[0];
  const float* targ = (const float*)d_in[1];
  float* out = (float*)d_out;
  double* accum = (double*)d_ws;

  // accum[0]=L1 sum, accum[1]=SSIM sum, accum[2] (first 4B) = done counter.
  hipMemsetAsync(d_ws, 0, 3 * sizeof(double), stream);

  dim3 grid(SSIM_W / TILE_W, SSIM_H / TILE_H, SSIM_PLANES);  // (8,16,96)
  ssim_l1_kernel<<<grid, 256, 0, stream>>>(pred, targ, accum, out);
}

// Round 3
// 467.940 us; speedup vs baseline: 1.5276x; 1.5276x over previous
//
#include <hip/hip_runtime.h>

#define SSIM_H 512
#define SSIM_W 512
#define SSIM_PLANES 96
#define TILE_H 32
#define TILE_W 64
#define N_TOTAL 25165824.0

// 11-tap Gaussian, sigma=1.5, normalized (matches reference _gaussian_window).
__global__ __launch_bounds__(256, 3)
void ssim_l1_kernel(const float* __restrict__ pred,
                    const float* __restrict__ targ,
                    double* __restrict__ accum) {
  const float w[11] = {
      0.00102838f, 0.00759876f, 0.03600077f, 0.10936069f, 0.21300553f,
      0.26601172f, 0.21300553f, 0.10936069f, 0.03600077f, 0.00759876f,
      0.00102838f};

  // 5 horizontal-conv planes: x, y, x*x, y*y, x*y. 42 halo rows x 64 cols.
  __shared__ __align__(16) float hc[5][TILE_H + 10][TILE_W];
  __shared__ float red[2][4];

  const int tid = (int)threadIdx.x;
  const int bx = (int)blockIdx.x, by = (int)blockIdx.y;
  const int row0 = by * TILE_H;  // first core row of tile
  const int col0 = bx * TILE_W;
  const size_t pbase = (size_t)blockIdx.z * (SSIM_H * SSIM_W);
  const float* __restrict__ xp = pred + pbase;
  const float* __restrict__ yp = targ + pbase;
  const bool xfast = (bx >= 1) && (bx <= 6);  // aligned window fully in-bounds

  float l1 = 0.0f;

  // ---- Phase A: horizontal conv for halo rows -5..36, 4-col chunks ----
  auto processA = [&](int item) {
    const int r = item >> 4;        // 0..41
    const int chunk = item & 15;
    const int irow = row0 - 5 + r;
    const int cb = col0 + (chunk << 2);  // first core col (multiple of 4)

    // A/B hold cols cb-8 .. cb+11 (5 aligned float4). Window = elements 3..16.
    float A[20], B[20];
    if ((unsigned)irow < (unsigned)SSIM_H) {
      const float* __restrict__ xr = xp + (size_t)irow * SSIM_W;
      const float* __restrict__ yr = yp + (size_t)irow * SSIM_W;
      if (xfast) {
        const float4* __restrict__ xa = (const float4*)(xr + (cb - 8));
        const float4* __restrict__ ya = (const float4*)(yr + (cb - 8));
#pragma unroll
        for (int q = 0; q < 5; ++q) {
          const float4 va = xa[q];
          const float4 vb = ya[q];
          A[4 * q + 0] = va.x; A[4 * q + 1] = va.y;
          A[4 * q + 2] = va.z; A[4 * q + 3] = va.w;
          B[4 * q + 0] = vb.x; B[4 * q + 1] = vb.y;
          B[4 * q + 2] = vb.z; B[4 * q + 3] = vb.w;
        }
      } else {
#pragma unroll
        for (int j = 0; j < 20; ++j) {
          const int c = cb - 8 + j;
          const bool ok = (unsigned)c < (unsigned)SSIM_W;
          A[j] = ok ? xr[c] : 0.0f;
          B[j] = ok ? yr[c] : 0.0f;
        }
      }
    } else {
#pragma unroll
      for (int j = 0; j < 20; ++j) { A[j] = 0.0f; B[j] = 0.0f; }
    }

    // L1 term on core rows; core cols are elements 8..11.
    if (r >= 5 && r < 37) {
#pragma unroll
      for (int o = 0; o < 4; ++o) l1 += fabsf(A[8 + o] - B[8 + o]);
    }

    float hx[4] = {0, 0, 0, 0}, hy[4] = {0, 0, 0, 0};
    float hxx[4] = {0, 0, 0, 0}, hyy[4] = {0, 0, 0, 0}, hxy[4] = {0, 0, 0, 0};
#pragma unroll
    for (int j = 0; j < 14; ++j) {  // window element j = col cb-5+j
      const float a = A[3 + j], b = B[3 + j];
      const float aa = a * a, bb = b * b, ab = a * b;
#pragma unroll
      for (int o = 0; o < 4; ++o) {
        const int k = j - o;
        if (k >= 0 && k < 11) {
          hx[o] += w[k] * a;
          hy[o] += w[k] * b;
          hxx[o] += w[k] * aa;
          hyy[o] += w[k] * bb;
          hxy[o] += w[k] * ab;
        }
      }
    }
    const int cc = chunk << 2;
    *(float4*)&hc[0][r][cc] = make_float4(hx[0], hx[1], hx[2], hx[3]);
    *(float4*)&hc[1][r][cc] = make_float4(hy[0], hy[1], hy[2], hy[3]);
    *(float4*)&hc[2][r][cc] = make_float4(hxx[0], hxx[1], hxx[2], hxx[3]);
    *(float4*)&hc[3][r][cc] = make_float4(hyy[0], hyy[1], hyy[2], hyy[3]);
    *(float4*)&hc[4][r][cc] = make_float4(hxy[0], hxy[1], hxy[2], hxy[3]);
  };

#pragma unroll
  for (int rd = 0; rd < 3; ++rd) {
    const int item = tid + rd * 256;
    if (item < 42 * 16) processA(item);
  }

  __syncthreads();

  // ---- Phase B: vertical conv + SSIM. 16 col-groups x 16 2-row bands. ----
  float ssim_sum = 0.0f;
  {
    const int g = tid & 15;   // float4 col group
    const int b = tid >> 4;   // 2-row band
    float acc[5][2][4];
#pragma unroll
    for (int p = 0; p < 5; ++p)
#pragma unroll
      for (int rr = 0; rr < 2; ++rr)
#pragma unroll
        for (int q = 0; q < 4; ++q) acc[p][rr][q] = 0.0f;

#pragma unroll
    for (int j = 0; j < 12; ++j) {
#pragma unroll
      for (int p = 0; p < 5; ++p) {
        const float4 v = *(const float4*)&hc[p][2 * b + j][g * 4];
        const float vv[4] = {v.x, v.y, v.z, v.w};
#pragma unroll
        for (int q = 0; q < 4; ++q) {
          if (j < 11) acc[p][0][q] += w[j] * vv[q];
          if (j >= 1) acc[p][1][q] += w[j - 1] * vv[q];
        }
      }
    }

    const float C1v = 1.0e-4f, C2v = 9.0e-4f;
#pragma unroll
    for (int rr = 0; rr < 2; ++rr) {
#pragma unroll
      for (int q = 0; q < 4; ++q) {
        const float mu1 = acc[0][rr][q], mu2 = acc[1][rr][q];
        const float cxx = acc[2][rr][q], cyy = acc[3][rr][q], cxy = acc[4][rr][q];
        const float m11 = mu1 * mu1, m22 = mu2 * mu2, m12 = mu1 * mu2;
        const float num = (2.0f * m12 + C1v) * (2.0f * (cxy - m12) + C2v);
        const float den = (m11 + m22 + C1v) * ((cxx - m11) + (cyy - m22) + C2v);
        ssim_sum += num / den;
      }
    }
  }

  // ---- Reduction: wave shuffle -> LDS -> block -> global double atomics ----
  float v0 = l1, v1 = ssim_sum;
#pragma unroll
  for (int off = 32; off > 0; off >>= 1) {
    v0 += __shfl_down(v0, off, 64);
    v1 += __shfl_down(v1, off, 64);
  }
  const int lane = tid & 63, wid = tid >> 6;
  if (lane == 0) { red[0][wid] = v0; red[1][wid] = v1; }
  __syncthreads();
  if (tid == 0) {
    const double L = (double)red[0][0] + (double)red[0][1] +
                     (double)red[0][2] + (double)red[0][3];
    const double S = (double)red[1][0] + (double)red[1][1] +
                     (double)red[1][2] + (double)red[1][3];
    atomicAdd(accum + 0, L);
    atomicAdd(accum + 1, S);
  }
}

__global__ void finalize_kernel(const double* __restrict__ accum,
                                float* __restrict__ out) {
  const double invN = 1.0 / N_TOTAL;
  const double l1m = accum[0] * invN;
  const double sm  = accum[1] * invN;
  out[0] = (float)(0.84 * l1m + 0.16 * (1.0 - sm));
}

extern "C" void kernel_launch(void* const* d_in, const int* in_sizes, int n_in,
                              void* d_out, int out_size, void* d_ws, size_t ws_size,
                              hipStream_t stream) {
  const float* pred = (const float*)d_in[0];
  const float* targ = (const float*)d_in[1];
  float* out = (float*)d_out;
  double* accum = (double*)d_ws;

  hipMemsetAsync(d_ws, 0, 2 * sizeof(double), stream);

  dim3 grid(SSIM_W / TILE_W, SSIM_H / TILE_H, SSIM_PLANES);  // (8,16,96)
  ssim_l1_kernel<<<grid, 256, 0, stream>>>(pred, targ, accum);
  finalize_kernel<<<1, 1, 0, stream>>>(accum, out);
}

// Round 4
// 455.630 us; speedup vs baseline: 1.5689x; 1.0270x over previous
//
#include <hip/hip_runtime.h>
#include <hip/hip_fp16.h>

#define SSIM_H 512
#define SSIM_W 512
#define SSIM_PLANES 96
#define TILE_H 32
#define TILE_W 64
#define N_TOTAL 25165824.0

struct __align__(8) h4 { __half2 lo, hi; };  // 4 fp16 values, one b64 LDS op

// 11-tap Gaussian, sigma=1.5, normalized (matches reference _gaussian_window).
__global__ __launch_bounds__(256, 6)
void ssim_l1_kernel(const float* __restrict__ pred,
                    const float* __restrict__ targ,
                    double* __restrict__ accum) {
  const float w[11] = {
      0.00102838f, 0.00759876f, 0.03600077f, 0.10936069f, 0.21300553f,
      0.26601172f, 0.21300553f, 0.10936069f, 0.03600077f, 0.00759876f,
      0.00102838f};

  // 5 horizontal-conv planes (x, y, xx, yy, xy) as fp16: 5*42*64*2 = 26.9 KB
  // -> 6 blocks/CU (vs 2 with fp32). This is the occupancy lever.
  __shared__ __align__(8) __half hc[5][TILE_H + 10][TILE_W];
  __shared__ float red[2][4];

  const int tid = (int)threadIdx.x;
  const int bx = (int)blockIdx.x, by = (int)blockIdx.y;
  const int row0 = by * TILE_H;
  const int col0 = bx * TILE_W;
  const size_t pbase = (size_t)blockIdx.z * (SSIM_H * SSIM_W);
  const float* __restrict__ xp = pred + pbase;
  const float* __restrict__ yp = targ + pbase;
  const bool xfast = (bx >= 1) && (bx <= 6);

  float l1 = 0.0f;

  // ---- Phase A: horizontal conv for halo rows -5..36, 4-col chunks ----
  auto processA = [&](int item) {
    const int r = item >> 4;        // 0..41
    const int chunk = item & 15;
    const int irow = row0 - 5 + r;
    const int cb = col0 + (chunk << 2);

    // A/B hold cols cb-8 .. cb+11 (5 aligned float4). Window = elements 3..16.
    float A[20], B[20];
    if ((unsigned)irow < (unsigned)SSIM_H) {
      const float* __restrict__ xr = xp + (size_t)irow * SSIM_W;
      const float* __restrict__ yr = yp + (size_t)irow * SSIM_W;
      if (xfast) {
        const float4* __restrict__ xa = (const float4*)(xr + (cb - 8));
        const float4* __restrict__ ya = (const float4*)(yr + (cb - 8));
#pragma unroll
        for (int q = 0; q < 5; ++q) {
          const float4 va = xa[q];
          const float4 vb = ya[q];
          A[4 * q + 0] = va.x; A[4 * q + 1] = va.y;
          A[4 * q + 2] = va.z; A[4 * q + 3] = va.w;
          B[4 * q + 0] = vb.x; B[4 * q + 1] = vb.y;
          B[4 * q + 2] = vb.z; B[4 * q + 3] = vb.w;
        }
      } else {
#pragma unroll
        for (int j = 0; j < 20; ++j) {
          const int c = cb - 8 + j;
          const bool ok = (unsigned)c < (unsigned)SSIM_W;
          A[j] = ok ? xr[c] : 0.0f;
          B[j] = ok ? yr[c] : 0.0f;
        }
      }
    } else {
#pragma unroll
      for (int j = 0; j < 20; ++j) { A[j] = 0.0f; B[j] = 0.0f; }
    }

    if (r >= 5 && r < 37) {
#pragma unroll
      for (int o = 0; o < 4; ++o) l1 += fabsf(A[8 + o] - B[8 + o]);
    }

    float hx[4] = {0, 0, 0, 0}, hy[4] = {0, 0, 0, 0};
    float hxx[4] = {0, 0, 0, 0}, hyy[4] = {0, 0, 0, 0}, hxy[4] = {0, 0, 0, 0};
#pragma unroll
    for (int j = 0; j < 14; ++j) {
      const float a = A[3 + j], b = B[3 + j];
      const float aa = a * a, bb = b * b, ab = a * b;
#pragma unroll
      for (int o = 0; o < 4; ++o) {
        const int k = j - o;
        if (k >= 0 && k < 11) {
          hx[o] += w[k] * a;
          hy[o] += w[k] * b;
          hxx[o] += w[k] * aa;
          hyy[o] += w[k] * bb;
          hxy[o] += w[k] * ab;
        }
      }
    }
    const int cc = chunk << 2;
    h4 s;
    s.lo = __float22half2_rn(make_float2(hx[0], hx[1]));
    s.hi = __float22half2_rn(make_float2(hx[2], hx[3]));
    *(h4*)&hc[0][r][cc] = s;
    s.lo = __float22half2_rn(make_float2(hy[0], hy[1]));
    s.hi = __float22half2_rn(make_float2(hy[2], hy[3]));
    *(h4*)&hc[1][r][cc] = s;
    s.lo = __float22half2_rn(make_float2(hxx[0], hxx[1]));
    s.hi = __float22half2_rn(make_float2(hxx[2], hxx[3]));
    *(h4*)&hc[2][r][cc] = s;
    s.lo = __float22half2_rn(make_float2(hyy[0], hyy[1]));
    s.hi = __float22half2_rn(make_float2(hyy[2], hyy[3]));
    *(h4*)&hc[3][r][cc] = s;
    s.lo = __float22half2_rn(make_float2(hxy[0], hxy[1]));
    s.hi = __float22half2_rn(make_float2(hxy[2], hxy[3]));
    *(h4*)&hc[4][r][cc] = s;
  };

#pragma unroll
  for (int rd = 0; rd < 3; ++rd) {
    const int item = tid + rd * 256;
    if (item < 42 * 16) processA(item);
  }

  __syncthreads();

  // ---- Phase B: vertical conv + SSIM. 16 col-groups x 16 2-row bands. ----
  float ssim_sum = 0.0f;
  {
    const int g = tid & 15;   // 4-col group
    const int b = tid >> 4;   // 2-row band
    float acc[5][2][4];
#pragma unroll
    for (int p = 0; p < 5; ++p)
#pragma unroll
      for (int rr = 0; rr < 2; ++rr)
#pragma unroll
        for (int q = 0; q < 4; ++q) acc[p][rr][q] = 0.0f;

#pragma unroll
    for (int j = 0; j < 12; ++j) {
#pragma unroll
      for (int p = 0; p < 5; ++p) {
        const h4 v = *(const h4*)&hc[p][2 * b + j][g * 4];
        // half->float folds into v_fma_mix_f32 on gfx950
        const float vv[4] = {__low2float(v.lo), __high2float(v.lo),
                             __low2float(v.hi), __high2float(v.hi)};
#pragma unroll
        for (int q = 0; q < 4; ++q) {
          if (j < 11) acc[p][0][q] += w[j] * vv[q];
          if (j >= 1) acc[p][1][q] += w[j - 1] * vv[q];
        }
      }
    }

    const float C1v = 1.0e-4f, C2v = 9.0e-4f;
#pragma unroll
    for (int rr = 0; rr < 2; ++rr) {
#pragma unroll
      for (int q = 0; q < 4; ++q) {
        const float mu1 = acc[0][rr][q], mu2 = acc[1][rr][q];
        const float cxx = acc[2][rr][q], cyy = acc[3][rr][q], cxy = acc[4][rr][q];
        const float m11 = mu1 * mu1, m22 = mu2 * mu2, m12 = mu1 * mu2;
        const float num = (2.0f * m12 + C1v) * (2.0f * (cxy - m12) + C2v);
        const float den = (m11 + m22 + C1v) * ((cxx - m11) + (cyy - m22) + C2v);
        ssim_sum += num / den;
      }
    }
  }

  // ---- Reduction: wave shuffle -> LDS -> block -> global double atomics ----
  float v0 = l1, v1 = ssim_sum;
#pragma unroll
  for (int off = 32; off > 0; off >>= 1) {
    v0 += __shfl_down(v0, off, 64);
    v1 += __shfl_down(v1, off, 64);
  }
  const int lane = tid & 63, wid = tid >> 6;
  if (lane == 0) { red[0][wid] = v0; red[1][wid] = v1; }
  __syncthreads();
  if (tid == 0) {
    const double L = (double)red[0][0] + (double)red[0][1] +
                     (double)red[0][2] + (double)red[0][3];
    const double S = (double)red[1][0] + (double)red[1][1] +
                     (double)red[1][2] + (double)red[1][3];
    atomicAdd(accum + 0, L);
    atomicAdd(accum + 1, S);
  }
}

__global__ void finalize_kernel(const double* __restrict__ accum,
                                float* __restrict__ out) {
  const double invN = 1.0 / N_TOTAL;
  const double l1m = accum[0] * invN;
  const double sm  = accum[1] * invN;
  out[0] = (float)(0.84 * l1m + 0.16 * (1.0 - sm));
}

extern "C" void kernel_launch(void* const* d_in, const int* in_sizes, int n_in,
                              void* d_out, int out_size, void* d_ws, size_t ws_size,
                              hipStream_t stream) {
  const float* pred = (const float*)d_in[0];
  const float* targ = (const float*)d_in[1];
  float* out = (float*)d_out;
  double* accum = (double*)d_ws;

  hipMemsetAsync(d_ws, 0, 2 * sizeof(double), stream);

  dim3 grid(SSIM_W / TILE_W, SSIM_H / TILE_H, SSIM_PLANES);  // (8,16,96)
  ssim_l1_kernel<<<grid, 256, 0, stream>>>(pred, targ, accum);
  finalize_kernel<<<1, 1, 0, stream>>>(accum, out);
}

// Round 5
// 362.483 us; speedup vs baseline: 1.9721x; 1.2570x over previous
//
#include <hip/hip_runtime.h>
#include <hip/hip_fp16.h>

#define SSIM_H 512
#define SSIM_W 512
#define SSIM_PLANES 96
#define TILE_H 32
#define TILE_W 64
#define TOTAL_BLOCKS (8 * 16 * 96)
#define N_TOTAL 25165824.0

struct __align__(8) h4 { __half2 lo, hi; };   // 4 fp16 values, one b64 LDS op
struct __align__(16) d2 { double x, y; };     // 16B partial-sum store

// 11-tap Gaussian, sigma=1.5, normalized (matches reference _gaussian_window).
__global__ __launch_bounds__(256, 6)
void ssim_l1_kernel(const float* __restrict__ pred,
                    const float* __restrict__ targ,
                    double* __restrict__ partials) {
  const float w[11] = {
      0.00102838f, 0.00759876f, 0.03600077f, 0.10936069f, 0.21300553f,
      0.26601172f, 0.21300553f, 0.10936069f, 0.03600077f, 0.00759876f,
      0.00102838f};

  // 5 horizontal-conv planes (x, y, xx, yy, xy) as fp16: 5*42*64*2 = 26.9 KB.
  __shared__ __align__(8) __half hc[5][TILE_H + 10][TILE_W];
  __shared__ float red[2][4];

  const int tid = (int)threadIdx.x;
  const int bx = (int)blockIdx.x, by = (int)blockIdx.y;
  const int row0 = by * TILE_H;
  const int col0 = bx * TILE_W;
  const size_t pbase = (size_t)blockIdx.z * (SSIM_H * SSIM_W);
  const float* __restrict__ xp = pred + pbase;
  const float* __restrict__ yp = targ + pbase;
  const bool xfast = (bx >= 1) && (bx <= 6);

  float l1 = 0.0f;

  // ---- Phase A: horizontal conv for halo rows -5..36, 4-col chunks ----
  auto processA = [&](int item) {
    const int r = item >> 4;        // 0..41
    const int chunk = item & 15;
    const int irow = row0 - 5 + r;
    const int cb = col0 + (chunk << 2);

    // A/B hold cols cb-8 .. cb+11 (5 aligned float4). Window = elements 3..16.
    float A[20], B[20];
    if ((unsigned)irow < (unsigned)SSIM_H) {
      const float* __restrict__ xr = xp + (size_t)irow * SSIM_W;
      const float* __restrict__ yr = yp + (size_t)irow * SSIM_W;
      if (xfast) {
        const float4* __restrict__ xa = (const float4*)(xr + (cb - 8));
        const float4* __restrict__ ya = (const float4*)(yr + (cb - 8));
#pragma unroll
        for (int q = 0; q < 5; ++q) {
          const float4 va = xa[q];
          const float4 vb = ya[q];
          A[4 * q + 0] = va.x; A[4 * q + 1] = va.y;
          A[4 * q + 2] = va.z; A[4 * q + 3] = va.w;
          B[4 * q + 0] = vb.x; B[4 * q + 1] = vb.y;
          B[4 * q + 2] = vb.z; B[4 * q + 3] = vb.w;
        }
      } else {
#pragma unroll
        for (int j = 0; j < 20; ++j) {
          const int c = cb - 8 + j;
          const bool ok = (unsigned)c < (unsigned)SSIM_W;
          A[j] = ok ? xr[c] : 0.0f;
          B[j] = ok ? yr[c] : 0.0f;
        }
      }
    } else {
#pragma unroll
      for (int j = 0; j < 20; ++j) { A[j] = 0.0f; B[j] = 0.0f; }
    }

    if (r >= 5 && r < 37) {
#pragma unroll
      for (int o = 0; o < 4; ++o) l1 += fabsf(A[8 + o] - B[8 + o]);
    }

    float hx[4] = {0, 0, 0, 0}, hy[4] = {0, 0, 0, 0};
    float hxx[4] = {0, 0, 0, 0}, hyy[4] = {0, 0, 0, 0}, hxy[4] = {0, 0, 0, 0};
#pragma unroll
    for (int j = 0; j < 14; ++j) {
      const float a = A[3 + j], b = B[3 + j];
      const float aa = a * a, bb = b * b, ab = a * b;
#pragma unroll
      for (int o = 0; o < 4; ++o) {
        const int k = j - o;
        if (k >= 0 && k < 11) {
          hx[o] += w[k] * a;
          hy[o] += w[k] * b;
          hxx[o] += w[k] * aa;
          hyy[o] += w[k] * bb;
          hxy[o] += w[k] * ab;
        }
      }
    }
    const int cc = chunk << 2;
    h4 s;
    s.lo = __float22half2_rn(make_float2(hx[0], hx[1]));
    s.hi = __float22half2_rn(make_float2(hx[2], hx[3]));
    *(h4*)&hc[0][r][cc] = s;
    s.lo = __float22half2_rn(make_float2(hy[0], hy[1]));
    s.hi = __float22half2_rn(make_float2(hy[2], hy[3]));
    *(h4*)&hc[1][r][cc] = s;
    s.lo = __float22half2_rn(make_float2(hxx[0], hxx[1]));
    s.hi = __float22half2_rn(make_float2(hxx[2], hxx[3]));
    *(h4*)&hc[2][r][cc] = s;
    s.lo = __float22half2_rn(make_float2(hyy[0], hyy[1]));
    s.hi = __float22half2_rn(make_float2(hyy[2], hyy[3]));
    *(h4*)&hc[3][r][cc] = s;
    s.lo = __float22half2_rn(make_float2(hxy[0], hxy[1]));
    s.hi = __float22half2_rn(make_float2(hxy[2], hxy[3]));
    *(h4*)&hc[4][r][cc] = s;
  };

#pragma unroll
  for (int rd = 0; rd < 3; ++rd) {
    const int item = tid + rd * 256;
    if (item < 42 * 16) processA(item);
  }

  __syncthreads();

  // ---- Phase B: vertical conv + SSIM. 16 col-groups x 16 2-row bands. ----
  float ssim_sum = 0.0f;
  {
    const int g = tid & 15;   // 4-col group
    const int b = tid >> 4;   // 2-row band
    float acc[5][2][4];
#pragma unroll
    for (int p = 0; p < 5; ++p)
#pragma unroll
      for (int rr = 0; rr < 2; ++rr)
#pragma unroll
        for (int q = 0; q < 4; ++q) acc[p][rr][q] = 0.0f;

#pragma unroll
    for (int j = 0; j < 12; ++j) {
#pragma unroll
      for (int p = 0; p < 5; ++p) {
        const h4 v = *(const h4*)&hc[p][2 * b + j][g * 4];
        const float vv[4] = {__low2float(v.lo), __high2float(v.lo),
                             __low2float(v.hi), __high2float(v.hi)};
#pragma unroll
        for (int q = 0; q < 4; ++q) {
          if (j < 11) acc[p][0][q] += w[j] * vv[q];
          if (j >= 1) acc[p][1][q] += w[j - 1] * vv[q];
        }
      }
    }

    const float C1v = 1.0e-4f, C2v = 9.0e-4f;
#pragma unroll
    for (int rr = 0; rr < 2; ++rr) {
#pragma unroll
      for (int q = 0; q < 4; ++q) {
        const float mu1 = acc[0][rr][q], mu2 = acc[1][rr][q];
        const float cxx = acc[2][rr][q], cyy = acc[3][rr][q], cxy = acc[4][rr][q];
        const float m11 = mu1 * mu1, m22 = mu2 * mu2, m12 = mu1 * mu2;
        const float num = (2.0f * m12 + C1v) * (2.0f * (cxy - m12) + C2v);
        const float den = (m11 + m22 + C1v) * ((cxx - m11) + (cyy - m22) + C2v);
        ssim_sum += num / den;
      }
    }
  }

  // ---- Reduction: wave shuffle -> LDS -> block -> PRIVATE partial slot ----
  // (round 4 post-mortem: 24576 fp64 atomics on one cache line across 8 XCDs
  //  serialized at ~14 ns each = the 350 µs wall. Plain per-block stores
  //  have zero contention.)
  float v0 = l1, v1 = ssim_sum;
#pragma unroll
  for (int off = 32; off > 0; off >>= 1) {
    v0 += __shfl_down(v0, off, 64);
    v1 += __shfl_down(v1, off, 64);
  }
  const int lane = tid & 63, wid = tid >> 6;
  if (lane == 0) { red[0][wid] = v0; red[1][wid] = v1; }
  __syncthreads();
  if (tid == 0) {
    d2 s;
    s.x = (double)red[0][0] + (double)red[0][1] +
          (double)red[0][2] + (double)red[0][3];
    s.y = (double)red[1][0] + (double)red[1][1] +
          (double)red[1][2] + (double)red[1][3];
    const int bid = ((int)blockIdx.z * (int)gridDim.y + (int)blockIdx.y) *
                        (int)gridDim.x + (int)blockIdx.x;
    *(d2*)(partials + 2 * bid) = s;
  }
}

__global__ __launch_bounds__(256)
void finalize_kernel(const double* __restrict__ partials,
                     float* __restrict__ out) {
  __shared__ double red[2][4];
  const int tid = (int)threadIdx.x;
  double L = 0.0, S = 0.0;
  for (int i = tid; i < TOTAL_BLOCKS; i += 256) {
    const d2 v = *(const d2*)(partials + 2 * i);
    L += v.x;
    S += v.y;
  }
#pragma unroll
  for (int off = 32; off > 0; off >>= 1) {
    L += __shfl_down(L, off, 64);
    S += __shfl_down(S, off, 64);
  }
  const int lane = tid & 63, wid = tid >> 6;
  if (lane == 0) { red[0][wid] = L; red[1][wid] = S; }
  __syncthreads();
  if (tid == 0) {
    const double Ls = red[0][0] + red[0][1] + red[0][2] + red[0][3];
    const double Ss = red[1][0] + red[1][1] + red[1][2] + red[1][3];
    const double invN = 1.0 / N_TOTAL;
    out[0] = (float)(0.84 * (Ls * invN) + 0.16 * (1.0 - Ss * invN));
  }
}

extern "C" void kernel_launch(void* const* d_in, const int* in_sizes, int n_in,
                              void* d_out, int out_size, void* d_ws, size_t ws_size,
                              hipStream_t stream) {
  const float* pred = (const float*)d_in[0];
  const float* targ = (const float*)d_in[1];
  float* out = (float*)d_out;
  double* partials = (double*)d_ws;  // 12288 * 2 doubles = 192 KB

  // No memset needed: every block unconditionally writes its slot.
  dim3 grid(SSIM_W / TILE_W, SSIM_H / TILE_H, SSIM_PLANES);  // (8,16,96)
  ssim_l1_kernel<<<grid, 256, 0, stream>>>(pred, targ, partials);
  finalize_kernel<<<1, 256, 0, stream>>>(partials, out);
}

// Round 6
// 276.158 us; speedup vs baseline: 2.5885x; 1.3126x over previous
//
#include <hip/hip_runtime.h>

#define SSIM_H 512
#define SSIM_W 512
#define PLANES 96
#define TILE 64
#define GRID_X (SSIM_W / TILE)
#define GRID_Y (SSIM_H / TILE)
#define TOTAL_BLOCKS (GRID_X * GRID_Y * PLANES)  // 6144
#define N_TOTAL 25165824.0

typedef _Float16 half4v __attribute__((ext_vector_type(4)));
typedef _Float16 half8v __attribute__((ext_vector_type(8)));
typedef float float4v __attribute__((ext_vector_type(4)));

struct __align__(16) d2 { double x, y; };

// Gaussian tap k (0..10), sigma=1.5: exp(-(k-5)^2/4.5) / 3.759233
__device__ __forceinline__ float gwf(int k) {
  const float d = (float)(k - 5);
  return __expf(-d * d / 4.5f) * 0.26601171702936207f;
}

// Both conv passes as mfma_f32_16x16x32_f16 against a banded weight matrix.
// Weight fragment value = w[8q + j - (lane&15)]; this serves as stage-1 B
// (B[k][n]=w[k-n]) and stage-2 A (A[i][kk]=w[kk-i]) with identical registers.
// H planes stored column-major [plane][col 64][row 84(pad)] f16: stage-1
// C-frag rows 4q+reg are contiguous -> b64 writes; stage-2 B-frag needs 8
// consecutive rows at fixed col -> two b64 reads. Stride 84 halves = 42
// dwords == 10 mod 32 -> 16 distinct banks across lanes (conflict-free).
__global__ __launch_bounds__(256, 3)
void ssim_l1_kernel(const float* __restrict__ pred,
                    const float* __restrict__ targ,
                    double* __restrict__ partials) {
  __shared__ _Float16 Hs[5][64][84];  // 53,760 B -> 3 blocks/CU
  __shared__ float red[2][4];

  const int tid = (int)threadIdx.x;
  const int wv = tid >> 6;    // wave: stage-1 col-group, stage-2 row-band
  const int lane = tid & 63;
  const int q = lane >> 4;    // quad
  const int m = lane & 15;    // A-row (stage1) / B-col (stage1) / etc.

  const int tr0 = (int)blockIdx.y * TILE;
  const int tc0 = (int)blockIdx.x * TILE;
  const size_t pbase = (size_t)blockIdx.z * (SSIM_H * SSIM_W);
  const float* __restrict__ xp = pred + pbase;
  const float* __restrict__ yp = targ + pbase;

  // Per-lane banded weight fragment.
  half8v wf;
#pragma unroll
  for (int j = 0; j < 8; ++j) {
    const int k = 8 * q + j - m;
    const float v = (k >= 0 && k <= 10) ? gwf(k) : 0.0f;
    wf[j] = (_Float16)v;
  }

  float l1 = 0.0f;

  // ---------------- Stage 1: horizontal conv -> Hs ----------------
  {
    const int cw = tc0 + 16 * wv;        // wave's output col-group (global)
    const int cbase = cw - 5 + 8 * q;    // first of 8 raw cols for this lane
    const bool cfast = (cbase >= 0) && (cbase + 7 < SSIM_W);

#pragma unroll
    for (int rg = 0; rg < 5; ++rg) {
      const int grow = tr0 - 5 + rg * 16 + m;  // raw image row (H row rg*16+m)
      float xf[8], yf[8];
      if ((unsigned)grow < (unsigned)SSIM_H) {
        const float* __restrict__ xr = xp + (size_t)grow * SSIM_W;
        const float* __restrict__ yr = yp + (size_t)grow * SSIM_W;
        if (cfast) {
          float4 a0, a1, b0, b1;
          __builtin_memcpy(&a0, xr + cbase, 16);
          __builtin_memcpy(&a1, xr + cbase + 4, 16);
          __builtin_memcpy(&b0, yr + cbase, 16);
          __builtin_memcpy(&b1, yr + cbase + 4, 16);
          xf[0] = a0.x; xf[1] = a0.y; xf[2] = a0.z; xf[3] = a0.w;
          xf[4] = a1.x; xf[5] = a1.y; xf[6] = a1.z; xf[7] = a1.w;
          yf[0] = b0.x; yf[1] = b0.y; yf[2] = b0.z; yf[3] = b0.w;
          yf[4] = b1.x; yf[5] = b1.y; yf[6] = b1.z; yf[7] = b1.w;
        } else {
#pragma unroll
          for (int j = 0; j < 8; ++j) {
            const int c = cbase + j;
            const bool ok = (unsigned)c < (unsigned)SSIM_W;
            xf[j] = ok ? xr[c] : 0.0f;
            yf[j] = ok ? yr[c] : 0.0f;
          }
        }
      } else {
#pragma unroll
        for (int j = 0; j < 8; ++j) { xf[j] = 0.0f; yf[j] = 0.0f; }
      }

      // Exact fp32 L1 on core pixels, counted exactly once:
      // core rows hr in [5,69), core cols k = 8q+j in [5,21).
      const int hr = rg * 16 + m;
      if (hr >= 5 && hr < 69) {
#pragma unroll
        for (int j = 0; j < 8; ++j) {
          const int k = 8 * q + j;
          if (k >= 5 && k < 21) l1 += fabsf(xf[j] - yf[j]);
        }
      }

      // Build f16 A-frags for the 5 planes.
      half8v ax, ay, axx, ayy, axy;
#pragma unroll
      for (int j = 0; j < 8; ++j) {
        ax[j]  = (_Float16)xf[j];
        ay[j]  = (_Float16)yf[j];
        axx[j] = (_Float16)(xf[j] * xf[j]);
        ayy[j] = (_Float16)(yf[j] * yf[j]);
        axy[j] = (_Float16)(xf[j] * yf[j]);
      }
      const float4v z = {0.0f, 0.0f, 0.0f, 0.0f};
      float4v c0 = __builtin_amdgcn_mfma_f32_16x16x32_f16(ax,  wf, z, 0, 0, 0);
      float4v c1 = __builtin_amdgcn_mfma_f32_16x16x32_f16(ay,  wf, z, 0, 0, 0);
      float4v c2 = __builtin_amdgcn_mfma_f32_16x16x32_f16(axx, wf, z, 0, 0, 0);
      float4v c3 = __builtin_amdgcn_mfma_f32_16x16x32_f16(ayy, wf, z, 0, 0, 0);
      float4v c4 = __builtin_amdgcn_mfma_f32_16x16x32_f16(axy, wf, z, 0, 0, 0);

      // C layout: col=lane&15, row=4q+reg (rows contiguous -> one b64/plane).
      const int hcol = 16 * wv + m;
      const int hrow = rg * 16 + 4 * q;
      half4v h;
      h[0] = (_Float16)c0[0]; h[1] = (_Float16)c0[1];
      h[2] = (_Float16)c0[2]; h[3] = (_Float16)c0[3];
      *(half4v*)&Hs[0][hcol][hrow] = h;
      h[0] = (_Float16)c1[0]; h[1] = (_Float16)c1[1];
      h[2] = (_Float16)c1[2]; h[3] = (_Float16)c1[3];
      *(half4v*)&Hs[1][hcol][hrow] = h;
      h[0] = (_Float16)c2[0]; h[1] = (_Float16)c2[1];
      h[2] = (_Float16)c2[2]; h[3] = (_Float16)c2[3];
      *(half4v*)&Hs[2][hcol][hrow] = h;
      h[0] = (_Float16)c3[0]; h[1] = (_Float16)c3[1];
      h[2] = (_Float16)c3[2]; h[3] = (_Float16)c3[3];
      *(half4v*)&Hs[3][hcol][hrow] = h;
      h[0] = (_Float16)c4[0]; h[1] = (_Float16)c4[1];
      h[2] = (_Float16)c4[2]; h[3] = (_Float16)c4[3];
      *(half4v*)&Hs[4][hcol][hrow] = h;
    }
  }

  __syncthreads();

  // ---------------- Stage 2: vertical conv + SSIM ----------------
  float ssim = 0.0f;
  {
    const float C1v = 1.0e-4f, C2v = 9.0e-4f;
#pragma unroll
    for (int cg = 0; cg < 4; ++cg) {
      const int hcol = 16 * cg + m;      // B-frag col n = lane&15
      const int hrow = 16 * wv + 8 * q;  // window row base (band = wv)
      const float4v z = {0.0f, 0.0f, 0.0f, 0.0f};
      float4v acc[5];
#pragma unroll
      for (int p = 0; p < 5; ++p) {
        const _Float16* hp = &Hs[p][hcol][hrow];
        half4v lo = *(const half4v*)hp;
        half4v hi = *(const half4v*)(hp + 4);
        half8v bf = __builtin_shufflevector(lo, hi, 0, 1, 2, 3, 4, 5, 6, 7);
        acc[p] = __builtin_amdgcn_mfma_f32_16x16x32_f16(wf, bf, z, 0, 0, 0);
      }
#pragma unroll
      for (int r = 0; r < 4; ++r) {
        const float mu1 = acc[0][r], mu2 = acc[1][r];
        const float exx = acc[2][r], eyy = acc[3][r], exy = acc[4][r];
        const float m11 = mu1 * mu1, m22 = mu2 * mu2, m12 = mu1 * mu2;
        const float num = (2.0f * m12 + C1v) * (2.0f * (exy - m12) + C2v);
        const float den = (m11 + m22 + C1v) *
                          ((exx - m11) + (eyy - m22) + C2v);
        ssim += num / den;
      }
    }
  }

  // ---- Reduction: wave shuffle -> LDS -> block -> private partial slot ----
  float v0 = l1, v1 = ssim;
#pragma unroll
  for (int off = 32; off > 0; off >>= 1) {
    v0 += __shfl_down(v0, off, 64);
    v1 += __shfl_down(v1, off, 64);
  }
  if (lane == 0) { red[0][wv] = v0; red[1][wv] = v1; }
  __syncthreads();
  if (tid == 0) {
    d2 s;
    s.x = (double)red[0][0] + (double)red[0][1] +
          (double)red[0][2] + (double)red[0][3];
    s.y = (double)red[1][0] + (double)red[1][1] +
          (double)red[1][2] + (double)red[1][3];
    const int bid = ((int)blockIdx.z * GRID_Y + (int)blockIdx.y) * GRID_X +
                    (int)blockIdx.x;
    *(d2*)(partials + 2 * bid) = s;
  }
}

__global__ __launch_bounds__(256)
void finalize_kernel(const double* __restrict__ partials,
                     float* __restrict__ out) {
  __shared__ double red[2][4];
  const int tid = (int)threadIdx.x;
  double L = 0.0, S = 0.0;
  for (int i = tid; i < TOTAL_BLOCKS; i += 256) {
    const d2 v = *(const d2*)(partials + 2 * i);
    L += v.x;
    S += v.y;
  }
#pragma unroll
  for (int off = 32; off > 0; off >>= 1) {
    L += __shfl_down(L, off, 64);
    S += __shfl_down(S, off, 64);
  }
  const int lane = tid & 63, wid = tid >> 6;
  if (lane == 0) { red[0][wid] = L; red[1][wid] = S; }
  __syncthreads();
  if (tid == 0) {
    const double Ls = red[0][0] + red[0][1] + red[0][2] + red[0][3];
    const double Ss = red[1][0] + red[1][1] + red[1][2] + red[1][3];
    const double invN = 1.0 / N_TOTAL;
    out[0] = (float)(0.84 * (Ls * invN) + 0.16 * (1.0 - Ss * invN));
  }
}

extern "C" void kernel_launch(void* const* d_in, const int* in_sizes, int n_in,
                              void* d_out, int out_size, void* d_ws, size_t ws_size,
                              hipStream_t stream) {
  const float* pred = (const float*)d_in[0];
  const float* targ = (const float*)d_in[1];
  float* out = (float*)d_out;
  double* partials = (double*)d_ws;  // 6144 * 2 doubles = 96 KB

  dim3 grid(GRID_X, GRID_Y, PLANES);  // (8, 8, 96)
  ssim_l1_kernel<<<grid, 256, 0, stream>>>(pred, targ, partials);
  finalize_kernel<<<1, 256, 0, stream>>>(partials, out);
}